// Round 1
// baseline (3549.018 us; speedup 1.0000x reference)
//
#include <hip/hip_runtime.h>
#include <math.h>

#define HH 16
#define SS 2048
#define DD 128
#define NROWS (HH * SS)            // 32768
#define OUTSZ (HH * SS * DD)       // 4194304 elems per output tensor

// ---------------------------------------------------------------------------
// helpers: 4-wide complex dot-product accumulate
// ---------------------------------------------------------------------------
__device__ __forceinline__ void cfma4(const float4 xr, const float4 xi,
                                      const float4 wr, const float4 wi,
                                      float& or_, float& oi_) {
    // or += xr.wr - xi.wi ; oi += xr.wi + xi.wr   (dot over 4 lanes)
    or_ = fmaf(xr.x, wr.x, or_); or_ = fmaf(-xi.x, wi.x, or_);
    or_ = fmaf(xr.y, wr.y, or_); or_ = fmaf(-xi.y, wi.y, or_);
    or_ = fmaf(xr.z, wr.z, or_); or_ = fmaf(-xi.z, wi.z, or_);
    or_ = fmaf(xr.w, wr.w, or_); or_ = fmaf(-xi.w, wi.w, or_);
    oi_ = fmaf(xr.x, wi.x, oi_); oi_ = fmaf(xi.x, wr.x, oi_);
    oi_ = fmaf(xr.y, wi.y, oi_); oi_ = fmaf(xi.y, wr.y, oi_);
    oi_ = fmaf(xr.z, wi.z, oi_); oi_ = fmaf(xi.z, wr.z, oi_);
    oi_ = fmaf(xr.w, wi.w, oi_); oi_ = fmaf(xi.w, wr.w, oi_);
}

__device__ __forceinline__ void sfma4(const float4 qr, const float4 qi,
                                      const float4 kr, const float4 ki,
                                      float& sr, float& si) {
    // sr += qr.kr + qi.ki ; si += qi.kr - qr.ki
    sr = fmaf(qr.x, kr.x, sr); sr = fmaf(qi.x, ki.x, sr);
    sr = fmaf(qr.y, kr.y, sr); sr = fmaf(qi.y, ki.y, sr);
    sr = fmaf(qr.z, kr.z, sr); sr = fmaf(qi.z, ki.z, sr);
    sr = fmaf(qr.w, kr.w, sr); sr = fmaf(qi.w, ki.w, sr);
    si = fmaf(qi.x, kr.x, si); si = fmaf(-qr.x, ki.x, si);
    si = fmaf(qi.y, kr.y, si); si = fmaf(-qr.y, ki.y, si);
    si = fmaf(qi.z, kr.z, si); si = fmaf(-qr.z, ki.z, si);
    si = fmaf(qi.w, kr.w, si); si = fmaf(-qr.w, ki.w, si);
}

// ---------------------------------------------------------------------------
// complex linear:  y = x @ W^T + b (+ pe).  GATE mode: x = g (*) a  (complex
// elementwise product of the g and a tensors) computed on the fly at load.
// 32 rows / block, 256 threads. W staged in LDS in 32-wide k-chunks.
// ---------------------------------------------------------------------------
template <bool GATE>
__global__ __launch_bounds__(256)
void clin_kernel(const float* __restrict__ xr, const float* __restrict__ xi,
                 const float* __restrict__ ar, const float* __restrict__ ai,
                 const float* __restrict__ wr, const float* __restrict__ wi,
                 const float* __restrict__ br, const float* __restrict__ bi,
                 const float* __restrict__ per, const float* __restrict__ pei,
                 float* __restrict__ yr, float* __restrict__ yi) {
    __shared__ float xs[2][32][DD + 4];   // +4 pad: bank stride 132 -> 4*r
    __shared__ float wsh[2][DD][36];      // [comp][col][k-chunk] pad 36

    const int t = threadIdx.x;
    const long rowbase = (long)blockIdx.x * 32;

    // ---- load x tile (and fuse gating if GATE) ----
    {
        const long base = rowbase * DD;
        for (int f = t; f < 32 * DD / 4; f += 256) {
            const int r = f >> 5;
            const int c4 = (f & 31) * 4;
            float4 a = *(const float4*)(xr + base + (long)r * DD + c4);
            float4 b = *(const float4*)(xi + base + (long)r * DD + c4);
            if (GATE) {
                float4 u = *(const float4*)(ar + base + (long)r * DD + c4);
                float4 v = *(const float4*)(ai + base + (long)r * DD + c4);
                float4 pr, pi;
                pr.x = a.x * u.x - b.x * v.x;  pi.x = a.x * v.x + b.x * u.x;
                pr.y = a.y * u.y - b.y * v.y;  pi.y = a.y * v.y + b.y * u.y;
                pr.z = a.z * u.z - b.z * v.z;  pi.z = a.z * v.z + b.z * u.z;
                pr.w = a.w * u.w - b.w * v.w;  pi.w = a.w * v.w + b.w * u.w;
                a = pr; b = pi;
            }
            *(float4*)&xs[0][r][c4] = a;
            *(float4*)&xs[1][r][c4] = b;
        }
    }

    const int r  = t >> 3;        // 0..31 row within tile
    const int cb = t & 7;         // col base; thread covers cols cb + 8*j
    float accr[16], acci[16];
#pragma unroll
    for (int j = 0; j < 16; ++j) { accr[j] = 0.f; acci[j] = 0.f; }

    for (int kc = 0; kc < 4; ++kc) {
        const int k0 = kc * 32;
        __syncthreads();   // protect wsh (prev iter) and xs (first iter)
        for (int f = t; f < DD * 8; f += 256) {
            const int c = f >> 3;
            const int kk = (f & 7) * 4;
            *(float4*)&wsh[0][c][kk] = *(const float4*)(wr + (long)c * DD + k0 + kk);
            *(float4*)&wsh[1][c][kk] = *(const float4*)(wi + (long)c * DD + k0 + kk);
        }
        __syncthreads();
#pragma unroll
        for (int kq = 0; kq < 8; ++kq) {
            const int k = kq * 4;
            const float4 xrv = *(const float4*)&xs[0][r][k0 + k];
            const float4 xiv = *(const float4*)&xs[1][r][k0 + k];
#pragma unroll
            for (int j = 0; j < 16; ++j) {
                const int c = cb + 8 * j;
                const float4 wrv = *(const float4*)&wsh[0][c][k];
                const float4 wiv = *(const float4*)&wsh[1][c][k];
                cfma4(xrv, xiv, wrv, wiv, accr[j], acci[j]);
            }
        }
    }

    // ---- epilogue: bias (+ pe), store ----
    const long R = rowbase + r;
#pragma unroll
    for (int j = 0; j < 16; ++j) {
        const int c = cb + 8 * j;
        float vr = accr[j] + br[c];
        float vi = acci[j] + bi[c];
        if (per != nullptr) {
            vr += per[R * DD + c];
            vi += pei[R * DD + c];
        }
        yr[R * DD + c] = vr;
        yi[R * DD + c] = vi;
    }
}

// ---------------------------------------------------------------------------
// fused flash attention with complex-magnitude scores.
// grid: (S/32 q-tiles, H heads), 256 threads.
// scores phase: thread (tq,tk) does a 2x2 microtile of the 32x32 score tile.
// PV phase: thread owns 4 rows x 4 cols of the 32x128 output accumulator.
// ---------------------------------------------------------------------------
__global__ __launch_bounds__(256)
void attn_kernel(const float* __restrict__ qr, const float* __restrict__ qi,
                 const float* __restrict__ kr, const float* __restrict__ ki,
                 const float* __restrict__ vr, const float* __restrict__ vi,
                 float* __restrict__ out_r, float* __restrict__ out_i) {
    __shared__ float qs[2][32][DD + 4];
    __shared__ float ks[2][32][DD + 4];
    __shared__ float vs[2][32][DD + 4];
    __shared__ float ps[32][37];          // probs; pad 37 -> conflict-free B reads
    __shared__ float m_s[32], l_s[32], alpha_s[32];

    const int t = threadIdx.x;
    const long hbase = (long)blockIdx.y * SS * DD;
    const int q0 = blockIdx.x * 32;
    const float scale = 0.08838834764831845f;   // 128^-0.5

    // load q tile
    {
        const long base = hbase + (long)q0 * DD;
        for (int f = t; f < 32 * DD / 4; f += 256) {
            const int r = f >> 5;
            const int c4 = (f & 31) * 4;
            *(float4*)&qs[0][r][c4] = *(const float4*)(qr + base + (long)r * DD + c4);
            *(float4*)&qs[1][r][c4] = *(const float4*)(qi + base + (long)r * DD + c4);
        }
    }
    if (t < 32) { m_s[t] = -1e30f; l_s[t] = 0.f; }

    const int tq2 = (t >> 4) * 2;   // q-row pair for score phase
    const int tk2 = (t & 15) * 2;   // k-row pair for score phase
    const int rq  = (t >> 5) * 4;   // 4-row group for PV phase
    const int cg  = (t & 31) * 4;   // 4-col group for PV phase

    float accr[4][4], acci[4][4];
#pragma unroll
    for (int a = 0; a < 4; ++a)
#pragma unroll
        for (int j = 0; j < 4; ++j) { accr[a][j] = 0.f; acci[a][j] = 0.f; }

    for (int kt = 0; kt < SS / 32; ++kt) {
        __syncthreads();   // prev-iter phase B done before overwriting ks/vs
        {
            const long base = hbase + (long)(kt * 32) * DD;
            for (int f = t; f < 32 * DD / 4; f += 256) {
                const int r = f >> 5;
                const int c4 = (f & 31) * 4;
                *(float4*)&ks[0][r][c4] = *(const float4*)(kr + base + (long)r * DD + c4);
                *(float4*)&ks[1][r][c4] = *(const float4*)(ki + base + (long)r * DD + c4);
                *(float4*)&vs[0][r][c4] = *(const float4*)(vr + base + (long)r * DD + c4);
                *(float4*)&vs[1][r][c4] = *(const float4*)(vi + base + (long)r * DD + c4);
            }
        }
        __syncthreads();

        // ---- phase A: 2x2 complex scores ----
        float sr[2][2] = {{0.f, 0.f}, {0.f, 0.f}};
        float si[2][2] = {{0.f, 0.f}, {0.f, 0.f}};
#pragma unroll 8
        for (int dq = 0; dq < DD / 4; ++dq) {
            const int d = dq * 4;
            float4 q_r[2], q_i[2], k_r[2], k_i[2];
            q_r[0] = *(const float4*)&qs[0][tq2][d];
            q_r[1] = *(const float4*)&qs[0][tq2 + 1][d];
            q_i[0] = *(const float4*)&qs[1][tq2][d];
            q_i[1] = *(const float4*)&qs[1][tq2 + 1][d];
            k_r[0] = *(const float4*)&ks[0][tk2][d];
            k_r[1] = *(const float4*)&ks[0][tk2 + 1][d];
            k_i[0] = *(const float4*)&ks[1][tk2][d];
            k_i[1] = *(const float4*)&ks[1][tk2 + 1][d];
#pragma unroll
            for (int a = 0; a < 2; ++a)
#pragma unroll
                for (int b = 0; b < 2; ++b)
                    sfma4(q_r[a], q_i[a], k_r[b], k_i[b], sr[a][b], si[a][b]);
        }

        float s[2][2];
#pragma unroll
        for (int a = 0; a < 2; ++a)
#pragma unroll
            for (int b = 0; b < 2; ++b)
                s[a][b] = sqrtf(fmaf(sr[a][b], sr[a][b],
                                fmaf(si[a][b], si[a][b], 1e-8f))) * scale;

        // online softmax bookkeeping (16-lane groups share a q-row pair)
        float rmax[2], mold[2], mnew[2], rsum[2], p[2][2];
#pragma unroll
        for (int a = 0; a < 2; ++a) rmax[a] = fmaxf(s[a][0], s[a][1]);
#pragma unroll
        for (int off = 1; off < 16; off <<= 1) {
            rmax[0] = fmaxf(rmax[0], __shfl_xor(rmax[0], off));
            rmax[1] = fmaxf(rmax[1], __shfl_xor(rmax[1], off));
        }
        mold[0] = m_s[tq2];     mold[1] = m_s[tq2 + 1];
        mnew[0] = fmaxf(mold[0], rmax[0]);
        mnew[1] = fmaxf(mold[1], rmax[1]);
#pragma unroll
        for (int a = 0; a < 2; ++a) {
            p[a][0] = __expf(s[a][0] - mnew[a]);
            p[a][1] = __expf(s[a][1] - mnew[a]);
            rsum[a] = p[a][0] + p[a][1];
        }
#pragma unroll
        for (int off = 1; off < 16; off <<= 1) {
            rsum[0] += __shfl_xor(rsum[0], off);
            rsum[1] += __shfl_xor(rsum[1], off);
        }
#pragma unroll
        for (int a = 0; a < 2; ++a) {
            ps[tq2 + a][tk2]     = p[a][0];
            ps[tq2 + a][tk2 + 1] = p[a][1];
        }
        if ((t & 15) == 0) {
#pragma unroll
            for (int a = 0; a < 2; ++a) {
                const int row = tq2 + a;
                const float al = __expf(mold[a] - mnew[a]);
                alpha_s[row] = al;
                l_s[row] = l_s[row] * al + rsum[a];
                m_s[row] = mnew[a];
            }
        }
        __syncthreads();

        // ---- phase B: rescale + PV accumulate ----
        float alv[4];
#pragma unroll
        for (int a = 0; a < 4; ++a) alv[a] = alpha_s[rq + a];
#pragma unroll
        for (int a = 0; a < 4; ++a)
#pragma unroll
            for (int j = 0; j < 4; ++j) { accr[a][j] *= alv[a]; acci[a][j] *= alv[a]; }

#pragma unroll 4
        for (int kk = 0; kk < 32; ++kk) {
            float pa[4];
#pragma unroll
            for (int a = 0; a < 4; ++a) pa[a] = ps[rq + a][kk];
            const float4 vrv = *(const float4*)&vs[0][kk][cg];
            const float4 viv = *(const float4*)&vs[1][kk][cg];
#pragma unroll
            for (int a = 0; a < 4; ++a) {
                accr[a][0] = fmaf(pa[a], vrv.x, accr[a][0]);
                accr[a][1] = fmaf(pa[a], vrv.y, accr[a][1]);
                accr[a][2] = fmaf(pa[a], vrv.z, accr[a][2]);
                accr[a][3] = fmaf(pa[a], vrv.w, accr[a][3]);
                acci[a][0] = fmaf(pa[a], viv.x, acci[a][0]);
                acci[a][1] = fmaf(pa[a], viv.y, acci[a][1]);
                acci[a][2] = fmaf(pa[a], viv.z, acci[a][2]);
                acci[a][3] = fmaf(pa[a], viv.w, acci[a][3]);
            }
        }
    }

    // ---- finalize: divide by softmax denom, store ----
    float linv[4];
#pragma unroll
    for (int a = 0; a < 4; ++a) linv[a] = 1.f / l_s[rq + a];
    const long obase = hbase + (long)q0 * DD;
#pragma unroll
    for (int a = 0; a < 4; ++a) {
        float4 o_r, o_i;
        o_r.x = accr[a][0] * linv[a]; o_r.y = accr[a][1] * linv[a];
        o_r.z = accr[a][2] * linv[a]; o_r.w = accr[a][3] * linv[a];
        o_i.x = acci[a][0] * linv[a]; o_i.y = acci[a][1] * linv[a];
        o_i.z = acci[a][2] * linv[a]; o_i.w = acci[a][3] * linv[a];
        *(float4*)(out_r + obase + (long)(rq + a) * DD + cg) = o_r;
        *(float4*)(out_i + obase + (long)(rq + a) * DD + cg) = o_i;
    }
}

// ---------------------------------------------------------------------------
extern "C" void kernel_launch(void* const* d_in, const int* in_sizes, int n_in,
                              void* d_out, int out_size, void* d_ws, size_t ws_size,
                              hipStream_t stream) {
    const float* q_r    = (const float*)d_in[0];
    const float* q_i    = (const float*)d_in[1];
    const float* k_r    = (const float*)d_in[2];
    const float* k_i    = (const float*)d_in[3];
    const float* v_r    = (const float*)d_in[4];
    const float* v_i    = (const float*)d_in[5];
    const float* pe_q_r = (const float*)d_in[6];
    const float* pe_q_i = (const float*)d_in[7];
    const float* pe_k_r = (const float*)d_in[8];
    const float* pe_k_i = (const float*)d_in[9];
    const float* qw_r = (const float*)d_in[10];
    const float* qw_i = (const float*)d_in[11];
    const float* qb_r = (const float*)d_in[12];
    const float* qb_i = (const float*)d_in[13];
    const float* kw_r = (const float*)d_in[14];
    const float* kw_i = (const float*)d_in[15];
    const float* kb_r = (const float*)d_in[16];
    const float* kb_i = (const float*)d_in[17];
    const float* vw_r = (const float*)d_in[18];
    const float* vw_i = (const float*)d_in[19];
    const float* vb_r = (const float*)d_in[20];
    const float* vb_i = (const float*)d_in[21];
    const float* gw_r = (const float*)d_in[22];
    const float* gw_i = (const float*)d_in[23];
    const float* gb_r = (const float*)d_in[24];
    const float* gb_i = (const float*)d_in[25];
    const float* ow_r = (const float*)d_in[26];
    const float* ow_i = (const float*)d_in[27];
    const float* ob_r = (const float*)d_in[28];
    const float* ob_i = (const float*)d_in[29];

    float* out_r = (float*)d_out;              // also temp for attn a_r
    float* out_i = out_r + (long)OUTSZ;        // also temp for attn a_i
    float* g_r   = out_r + 2L * OUTSZ;
    float* g_i   = out_r + 3L * OUTSZ;

    float* ws  = (float*)d_ws;                 // 6 x OUTSZ floats = 96 MiB
    float* pqr = ws + 0L * OUTSZ;
    float* pqi = ws + 1L * OUTSZ;
    float* pkr = ws + 2L * OUTSZ;
    float* pki = ws + 3L * OUTSZ;
    float* pvr = ws + 4L * OUTSZ;
    float* pvi = ws + 5L * OUTSZ;

    const dim3 blk(256);
    const dim3 lin_grid(NROWS / 32);

    // projections
    clin_kernel<false><<<lin_grid, blk, 0, stream>>>(
        q_r, q_i, nullptr, nullptr, qw_r, qw_i, qb_r, qb_i, pe_q_r, pe_q_i, pqr, pqi);
    clin_kernel<false><<<lin_grid, blk, 0, stream>>>(
        k_r, k_i, nullptr, nullptr, kw_r, kw_i, kb_r, kb_i, pe_k_r, pe_k_i, pkr, pki);
    clin_kernel<false><<<lin_grid, blk, 0, stream>>>(
        v_r, v_i, nullptr, nullptr, vw_r, vw_i, vb_r, vb_i, nullptr, nullptr, pvr, pvi);
    clin_kernel<false><<<lin_grid, blk, 0, stream>>>(
        q_r, q_i, nullptr, nullptr, gw_r, gw_i, gb_r, gb_i, nullptr, nullptr, g_r, g_i);

    // fused flash attention (a_r, a_i parked in d_out slots 0,1)
    attn_kernel<<<dim3(SS / 32, HH), blk, 0, stream>>>(
        pqr, pqi, pkr, pki, pvr, pvi, out_r, out_i);

    // gate + output projection, in-place over slots 0,1 (block reads its own
    // 32 rows into LDS before writing them; rows are block-disjoint -> safe)
    clin_kernel<true><<<lin_grid, blk, 0, stream>>>(
        g_r, g_i, out_r, out_i, ow_r, ow_i, ob_r, ob_i, nullptr, nullptr, out_r, out_i);
}

// Round 2
// 836.900 us; speedup vs baseline: 4.2407x; 4.2407x over previous
//
#include <hip/hip_runtime.h>
#include <math.h>

#define HH 16
#define SS 2048
#define DD 128
#define NROWS (HH * SS)            // 32768
#define OUTSZ (HH * SS * DD)       // 4194304 elems per tensor

typedef __attribute__((ext_vector_type(8))) short bf16x8;
typedef __attribute__((ext_vector_type(4))) float f32x4;
typedef __attribute__((ext_vector_type(8))) unsigned short u16x8;

#define MFMA16(a, b, c) __builtin_amdgcn_mfma_f32_16x16x32_bf16(a, b, c, 0, 0, 0)

__device__ __forceinline__ unsigned short f2bf(float f) {
    unsigned u = __float_as_uint(f);
    return (unsigned short)((u + 0x7FFFu + ((u >> 16) & 1u)) >> 16);   // RNE
}
__device__ __forceinline__ bf16x8 negf(bf16x8 a) {
    bf16x8 r;
#pragma unroll
    for (int j = 0; j < 8; ++j) r[j] = (short)(a[j] ^ (short)0x8000);
    return r;
}

// ---------------------------------------------------------------------------
// MFMA complex linear: y = x @ W^T + b (+pe).  GATE: x = xr,xi (*) gr,gi
// complex product computed at fragment build. 64 rows/block, 256 thr, 4 waves.
// W (both comps) staged bf16 in LDS once; x read straight into A-fragments.
// ---------------------------------------------------------------------------
template <bool GATE, bool OUTBF>
__global__ __launch_bounds__(256, 2)
void clin_mfma(const float* __restrict__ xr, const float* __restrict__ xi,
               const float* __restrict__ gr, const float* __restrict__ gi,
               const float* __restrict__ wr, const float* __restrict__ wi,
               const float* __restrict__ br, const float* __restrict__ bi,
               const float* __restrict__ per, const float* __restrict__ pei,
               void* __restrict__ yr_, void* __restrict__ yi_) {
    __shared__ unsigned short wsh[2][DD][136];   // bf16, pitch 136 (272B, 16B-aligned)

    const int t = threadIdx.x;
    // ---- stage W fp32->bf16 (4096 groups of 8 elems) ----
#pragma unroll
    for (int u = 0; u < 16; ++u) {
        const int f = t + 256 * u;
        const int c = f >> 11;
        const int rem = f & 2047;
        const int row = rem >> 4;
        const int g8 = (rem & 15) * 8;
        const float* src = (c ? wi : wr) + row * DD + g8;
        const float4 a = *(const float4*)src;
        const float4 b = *(const float4*)(src + 4);
        unsigned short tmp[8] = {f2bf(a.x), f2bf(a.y), f2bf(a.z), f2bf(a.w),
                                 f2bf(b.x), f2bf(b.y), f2bf(b.z), f2bf(b.w)};
        *(u16x8*)&wsh[c][row][g8] = *(u16x8*)tmp;
    }

    const int w = t >> 6, lane = t & 63;
    const int lm = lane & 15, quad = lane >> 4;
    const long m0 = (long)blockIdx.x * 64 + w * 16;

    // ---- A fragments: rows m0+lm, k = dk*32 + quad*8 + j ----
    bf16x8 xrf[4], xif[4];
    {
        const long rbase = (m0 + lm) * DD;
#pragma unroll
        for (int dk = 0; dk < 4; ++dk) {
            const long o = rbase + dk * 32 + quad * 8;
            const float4 a0 = *(const float4*)(xr + o);
            const float4 a1 = *(const float4*)(xr + o + 4);
            const float4 b0 = *(const float4*)(xi + o);
            const float4 b1 = *(const float4*)(xi + o + 4);
            float fr[8] = {a0.x, a0.y, a0.z, a0.w, a1.x, a1.y, a1.z, a1.w};
            float fi[8] = {b0.x, b0.y, b0.z, b0.w, b1.x, b1.y, b1.z, b1.w};
            if (GATE) {
                const float4 c0 = *(const float4*)(gr + o);
                const float4 c1 = *(const float4*)(gr + o + 4);
                const float4 d0 = *(const float4*)(gi + o);
                const float4 d1 = *(const float4*)(gi + o + 4);
                const float ur[8] = {c0.x, c0.y, c0.z, c0.w, c1.x, c1.y, c1.z, c1.w};
                const float ui[8] = {d0.x, d0.y, d0.z, d0.w, d1.x, d1.y, d1.z, d1.w};
#pragma unroll
                for (int j = 0; j < 8; ++j) {
                    const float pr = fr[j] * ur[j] - fi[j] * ui[j];
                    const float pi = fr[j] * ui[j] + fi[j] * ur[j];
                    fr[j] = pr; fi[j] = pi;
                }
            }
#pragma unroll
            for (int j = 0; j < 8; ++j) {
                xrf[dk][j] = (short)f2bf(fr[j]);
                xif[dk][j] = (short)f2bf(fi[j]);
            }
        }
    }

    f32x4 Or[8], Oi[8];
    const f32x4 z = {0.f, 0.f, 0.f, 0.f};
#pragma unroll
    for (int nt = 0; nt < 8; ++nt) { Or[nt] = z; Oi[nt] = z; }

    __syncthreads();

#pragma unroll
    for (int dk = 0; dk < 4; ++dk) {
        const bf16x8 nxi = negf(xif[dk]);
#pragma unroll
        for (int nt = 0; nt < 8; ++nt) {
            const int off = dk * 32 + quad * 8;
            const bf16x8 wrf = *(bf16x8*)&wsh[0][nt * 16 + lm][off];
            const bf16x8 wif = *(bf16x8*)&wsh[1][nt * 16 + lm][off];
            Or[nt] = MFMA16(xrf[dk], wrf, Or[nt]);
            Or[nt] = MFMA16(nxi,     wif, Or[nt]);
            Oi[nt] = MFMA16(xrf[dk], wif, Oi[nt]);
            Oi[nt] = MFMA16(xif[dk], wrf, Oi[nt]);
        }
    }

    // ---- epilogue: C layout row = quad*4+reg, col = nt*16+lm ----
#pragma unroll
    for (int nt = 0; nt < 8; ++nt) {
        const int c = nt * 16 + lm;
        const float bra = br[c], bia = bi[c];
#pragma unroll
        for (int reg = 0; reg < 4; ++reg) {
            const long R = m0 + quad * 4 + reg;
            float vr = Or[nt][reg] + bra;
            float vi = Oi[nt][reg] + bia;
            if (per != nullptr) {
                vr += per[R * DD + c];
                vi += pei[R * DD + c];
            }
            if (OUTBF) {
                ((unsigned short*)yr_)[R * DD + c] = f2bf(vr);
                ((unsigned short*)yi_)[R * DD + c] = f2bf(vi);
            } else {
                ((float*)yr_)[R * DD + c] = vr;
                ((float*)yi_)[R * DD + c] = vi;
            }
        }
    }
}

// ---------------------------------------------------------------------------
// MFMA flash attention, complex-magnitude scores. bf16 q,k,v inputs.
// grid (S/64, H), 256 thr = 4 waves; wave w owns q rows q0+w*16..+15.
// Bk=32 per iter. K row-major LDS; V transposed in LDS; P via LDS roundtrip.
// Online softmax: per-reg running max with ballot-gated lazy rescale.
// ---------------------------------------------------------------------------
__global__ __launch_bounds__(256, 3)
void attn_mfma(const unsigned short* __restrict__ qr, const unsigned short* __restrict__ qi,
               const unsigned short* __restrict__ kr, const unsigned short* __restrict__ ki,
               const unsigned short* __restrict__ vr, const unsigned short* __restrict__ vi,
               float* __restrict__ out_r, float* __restrict__ out_i) {
    __shared__ unsigned short ks[2][32][136];   // 17408 B
    __shared__ unsigned short vt[2][DD][40];    // 20480 B (V transposed [d][k])
    __shared__ unsigned short ps[64][40];       //  5120 B (P, bf16)

    const int t = threadIdx.x;
    const int w = t >> 6, lane = t & 63;
    const int lm = lane & 15, quad = lane >> 4;
    const long hbase = (long)blockIdx.y * SS * DD;
    const int q0 = blockIdx.x * 64;
    const float scale = 0.08838834764831845f;   // 128^-0.5

    // ---- resident Q fragments (A layout) ----
    bf16x8 qrf[4], qif[4], nqrf[4];
    {
        const long rb = hbase + (long)(q0 + w * 16 + lm) * DD;
#pragma unroll
        for (int dk = 0; dk < 4; ++dk) {
            qrf[dk] = *(const bf16x8*)(qr + rb + dk * 32 + quad * 8);
            qif[dk] = *(const bf16x8*)(qi + rb + dk * 32 + quad * 8);
            nqrf[dk] = negf(qrf[dk]);
        }
    }

    f32x4 Or[8], Oi[8];
    const f32x4 z = {0.f, 0.f, 0.f, 0.f};
#pragma unroll
    for (int nt = 0; nt < 8; ++nt) { Or[nt] = z; Oi[nt] = z; }
    float m_st[4] = {-1e30f, -1e30f, -1e30f, -1e30f};
    float l_st[4] = {0.f, 0.f, 0.f, 0.f};

    for (int kt = 0; kt < SS / 32; ++kt) {
        const int k0 = kt * 32;
        __syncthreads();   // prev-iter reads of ks/vt done
        // ---- stage K (row-major bf16) ----
#pragma unroll
        for (int u = 0; u < 4; ++u) {
            const int f = t + 256 * u;
            const int c = f >> 9;
            const int rem = f & 511;
            const int r = rem >> 4;
            const int g8 = (rem & 15) * 8;
            const unsigned short* src = (c ? ki : kr) + hbase + (long)(k0 + r) * DD + g8;
            *(u16x8*)&ks[c][r][g8] = *(const u16x8*)src;
        }
        // ---- stage V transposed: vt[c][d][k] ----
#pragma unroll
        for (int u = 0; u < 2; ++u) {
            const int p = t + 256 * u;
            const int c = p >> 8;
            const int rem = p & 255;
            const int s2 = (rem & 15) * 2;
            const int d8 = (rem >> 4) * 8;
            const unsigned short* src = (c ? vi : vr) + hbase + (long)(k0 + s2) * DD + d8;
            const u16x8 a = *(const u16x8*)src;
            const u16x8 b = *(const u16x8*)(src + DD);
#pragma unroll
            for (int j = 0; j < 8; ++j) {
                const unsigned val = (unsigned)a[j] | ((unsigned)b[j] << 16);
                *(unsigned*)&vt[c][d8 + j][s2] = val;
            }
        }
        __syncthreads();

        // ---- scores: two 16x16 tiles (k cols 0-15, 16-31) ----
        f32x4 sr0 = z, sr1 = z, si0 = z, si1 = z;
#pragma unroll
        for (int dk = 0; dk < 4; ++dk) {
            const int off = dk * 32 + quad * 8;
            const bf16x8 kr0 = *(bf16x8*)&ks[0][lm][off];
            const bf16x8 ki0 = *(bf16x8*)&ks[1][lm][off];
            const bf16x8 kr1 = *(bf16x8*)&ks[0][16 + lm][off];
            const bf16x8 ki1 = *(bf16x8*)&ks[1][16 + lm][off];
            sr0 = MFMA16(qrf[dk], kr0, sr0);  sr0 = MFMA16(qif[dk], ki0, sr0);
            si0 = MFMA16(qif[dk], kr0, si0);  si0 = MFMA16(nqrf[dk], ki0, si0);
            sr1 = MFMA16(qrf[dk], kr1, sr1);  sr1 = MFMA16(qif[dk], ki1, sr1);
            si1 = MFMA16(qif[dk], kr1, si1);  si1 = MFMA16(nqrf[dk], ki1, si1);
        }

        // ---- online softmax, per reg (= per q-row of this lane group) ----
#pragma unroll
        for (int reg = 0; reg < 4; ++reg) {
            const float s0 = sqrtf(fmaf(sr0[reg], sr0[reg],
                                   fmaf(si0[reg], si0[reg], 1e-8f))) * scale;
            const float s1 = sqrtf(fmaf(sr1[reg], sr1[reg],
                                   fmaf(si1[reg], si1[reg], 1e-8f))) * scale;
            float rm = fmaxf(s0, s1);
#pragma unroll
            for (int off = 1; off < 16; off <<= 1) rm = fmaxf(rm, __shfl_xor(rm, off));
            if (__ballot(rm > m_st[reg])) {        // wave-uniform lazy rescale
                const float mnew = fmaxf(m_st[reg], rm);
                const float al = __expf(m_st[reg] - mnew);
                m_st[reg] = mnew;
                l_st[reg] *= al;
#pragma unroll
                for (int nt = 0; nt < 8; ++nt) { Or[nt][reg] *= al; Oi[nt][reg] *= al; }
            }
            const float p0 = __expf(s0 - m_st[reg]);
            const float p1 = __expf(s1 - m_st[reg]);
            l_st[reg] += p0 + p1;
            ps[w * 16 + quad * 4 + reg][lm]      = f2bf(p0);
            ps[w * 16 + quad * 4 + reg][16 + lm] = f2bf(p1);
        }

        // ---- PV: P (A layout via LDS, intra-wave) x V^T tiles ----
        const bf16x8 pf = *(bf16x8*)&ps[w * 16 + lm][quad * 8];
#pragma unroll
        for (int nt = 0; nt < 8; ++nt) {
            const bf16x8 vrf = *(bf16x8*)&vt[0][nt * 16 + lm][quad * 8];
            const bf16x8 vif = *(bf16x8*)&vt[1][nt * 16 + lm][quad * 8];
            Or[nt] = MFMA16(pf, vrf, Or[nt]);
            Oi[nt] = MFMA16(pf, vif, Oi[nt]);
        }
    }

    // ---- finalize: reduce l across 16-lane group, scale, store ----
    float linv[4];
#pragma unroll
    for (int reg = 0; reg < 4; ++reg) {
        float l = l_st[reg];
#pragma unroll
        for (int off = 1; off < 16; off <<= 1) l += __shfl_xor(l, off);
        linv[reg] = 1.f / l;
    }
    const long ob = hbase + (long)(q0 + w * 16) * DD;
#pragma unroll
    for (int nt = 0; nt < 8; ++nt) {
        const int c = nt * 16 + lm;
#pragma unroll
        for (int reg = 0; reg < 4; ++reg) {
            const long R = ob + (long)(quad * 4 + reg) * DD + c;
            out_r[R] = Or[nt][reg] * linv[reg];
            out_i[R] = Oi[nt][reg] * linv[reg];
        }
    }
}

// ---------------------------------------------------------------------------
extern "C" void kernel_launch(void* const* d_in, const int* in_sizes, int n_in,
                              void* d_out, int out_size, void* d_ws, size_t ws_size,
                              hipStream_t stream) {
    const float* q_r    = (const float*)d_in[0];
    const float* q_i    = (const float*)d_in[1];
    const float* k_r    = (const float*)d_in[2];
    const float* k_i    = (const float*)d_in[3];
    const float* v_r    = (const float*)d_in[4];
    const float* v_i    = (const float*)d_in[5];
    const float* pe_q_r = (const float*)d_in[6];
    const float* pe_q_i = (const float*)d_in[7];
    const float* pe_k_r = (const float*)d_in[8];
    const float* pe_k_i = (const float*)d_in[9];
    const float* qw_r = (const float*)d_in[10];
    const float* qw_i = (const float*)d_in[11];
    const float* qb_r = (const float*)d_in[12];
    const float* qb_i = (const float*)d_in[13];
    const float* kw_r = (const float*)d_in[14];
    const float* kw_i = (const float*)d_in[15];
    const float* kb_r = (const float*)d_in[16];
    const float* kb_i = (const float*)d_in[17];
    const float* vw_r = (const float*)d_in[18];
    const float* vw_i = (const float*)d_in[19];
    const float* vb_r = (const float*)d_in[20];
    const float* vb_i = (const float*)d_in[21];
    const float* gw_r = (const float*)d_in[22];
    const float* gw_i = (const float*)d_in[23];
    const float* gb_r = (const float*)d_in[24];
    const float* gb_i = (const float*)d_in[25];
    const float* ow_r = (const float*)d_in[26];
    const float* ow_i = (const float*)d_in[27];
    const float* ob_r = (const float*)d_in[28];
    const float* ob_i = (const float*)d_in[29];

    float* out_r = (float*)d_out;              // attn a_r temp, then final out_r
    float* out_i = out_r + (long)OUTSZ;
    float* g_r   = out_r + 2L * OUTSZ;
    float* g_i   = out_r + 3L * OUTSZ;

    unsigned short* ws = (unsigned short*)d_ws; // 6 x 8 MiB bf16
    unsigned short* pqr = ws + 0L * OUTSZ;
    unsigned short* pqi = ws + 1L * OUTSZ;
    unsigned short* pkr = ws + 2L * OUTSZ;
    unsigned short* pki = ws + 3L * OUTSZ;
    unsigned short* pvr = ws + 4L * OUTSZ;
    unsigned short* pvi = ws + 5L * OUTSZ;

    const dim3 blk(256);
    const dim3 lin_grid(NROWS / 64);

    clin_mfma<false, true><<<lin_grid, blk, 0, stream>>>(
        q_r, q_i, nullptr, nullptr, qw_r, qw_i, qb_r, qb_i, pe_q_r, pe_q_i, pqr, pqi);
    clin_mfma<false, true><<<lin_grid, blk, 0, stream>>>(
        k_r, k_i, nullptr, nullptr, kw_r, kw_i, kb_r, kb_i, pe_k_r, pe_k_i, pkr, pki);
    clin_mfma<false, true><<<lin_grid, blk, 0, stream>>>(
        v_r, v_i, nullptr, nullptr, vw_r, vw_i, vb_r, vb_i, nullptr, nullptr, pvr, pvi);
    clin_mfma<false, false><<<lin_grid, blk, 0, stream>>>(
        q_r, q_i, nullptr, nullptr, gw_r, gw_i, gb_r, gb_i, nullptr, nullptr, g_r, g_i);

    attn_mfma<<<dim3(SS / 64, HH), blk, 0, stream>>>(
        pqr, pqi, pkr, pki, pvr, pvi, out_r, out_i);

    // gate + o-projection, in-place over d_out slots 0,1 (each wave reads its
    // 16 rows into fragments before its epilogue stores those same rows)
    clin_mfma<true, false><<<lin_grid, blk, 0, stream>>>(
        g_r, g_i, out_r, out_i, ow_r, ow_i, ob_r, ob_i, nullptr, nullptr, out_r, out_i);
}